// Round 8
// baseline (37900.159 us; speedup 1.0000x reference)
//
#include <hip/hip_runtime.h>
#include <math.h>

#define SEQ    2048
#define BATCH  32
#define IN_DIM 512
#define HID    512
#define GATES  (4*HID)   // 2048

typedef __attribute__((ext_vector_type(4))) float f32x4;
typedef __attribute__((ext_vector_type(2))) float f32x2;

__device__ inline float fsigmoid(float x) {
    return 1.f / (1.f + __expf(-x));
}
__device__ inline float ftanh(float x) {
    return 1.f - 2.f / (1.f + __expf(2.f * x));
}

// ---------------------------------------------------------------------------
// x_proj GEMM:  xp[m][n] = sum_k x[m][k]*Wih[n][k] + bih[n] + bhh[n]
// ---------------------------------------------------------------------------
__global__ __launch_bounds__(256) void xproj_kernel(
    const float* __restrict__ x,     // [M][512]
    const float* __restrict__ Wih,   // [2048][512]
    const float* __restrict__ bih,
    const float* __restrict__ bhh,
    float* __restrict__ xp,          // [M][2048]
    int M)
{
    __shared__ float As[16][132];
    __shared__ float Bs[16][132];
    const int tid = threadIdx.x;
    const int nb = blockIdx.x & 15;
    const int mb = blockIdx.x >> 4;
    const int m0 = mb * 128, n0 = nb * 128;
    const int tx = tid & 15, ty = tid >> 4;

    float acc[8][8];
#pragma unroll
    for (int i = 0; i < 8; ++i)
#pragma unroll
        for (int j = 0; j < 8; ++j) acc[i][j] = 0.f;

    for (int kc = 0; kc < 512; kc += 16) {
#pragma unroll
        for (int h = 0; h < 2; ++h) {
            int f4 = tid + 256 * h;
            int r = f4 >> 2, u = f4 & 3;
            float4 va = *(const float4*)(x + (size_t)(m0 + r) * 512 + kc + 4 * u);
            As[4*u+0][r] = va.x; As[4*u+1][r] = va.y;
            As[4*u+2][r] = va.z; As[4*u+3][r] = va.w;
            float4 vb = *(const float4*)(Wih + (size_t)(n0 + r) * 512 + kc + 4 * u);
            Bs[4*u+0][r] = vb.x; Bs[4*u+1][r] = vb.y;
            Bs[4*u+2][r] = vb.z; Bs[4*u+3][r] = vb.w;
        }
        __syncthreads();
#pragma unroll
        for (int kk = 0; kk < 16; ++kk) {
            float4 a0 = *(const float4*)&As[kk][tx * 8];
            float4 a1 = *(const float4*)&As[kk][tx * 8 + 4];
            float4 b0 = *(const float4*)&Bs[kk][ty * 8];
            float4 b1 = *(const float4*)&Bs[kk][ty * 8 + 4];
            float av[8] = {a0.x,a0.y,a0.z,a0.w,a1.x,a1.y,a1.z,a1.w};
            float bv[8] = {b0.x,b0.y,b0.z,b0.w,b1.x,b1.y,b1.z,b1.w};
#pragma unroll
            for (int i = 0; i < 8; ++i)
#pragma unroll
                for (int j = 0; j < 8; ++j) acc[i][j] += av[i] * bv[j];
        }
        __syncthreads();
    }

    float bias[8];
#pragma unroll
    for (int j = 0; j < 8; ++j) {
        int n = n0 + ty * 8 + j;
        bias[j] = bih[n] + bhh[n];
    }
#pragma unroll
    for (int i = 0; i < 8; ++i) {
        size_t base = (size_t)(m0 + tx * 8 + i) * GATES + n0 + ty * 8;
        float4 v0 = make_float4(acc[i][0]+bias[0], acc[i][1]+bias[1],
                                acc[i][2]+bias[2], acc[i][3]+bias[3]);
        float4 v1 = make_float4(acc[i][4]+bias[4], acc[i][5]+bias[5],
                                acc[i][6]+bias[6], acc[i][7]+bias[7]);
        *(float4*)(xp + base)     = v0;
        *(float4*)(xp + base + 4) = v1;
    }
}

// ---------------------------------------------------------------------------
// Scan. 8 independent groups (4 batches) x 32 WGs (16 hid each).
// h exchange: 8B granules {h, tagf}, exact-equality tags, parity double-buffer.
// Exchange rides the L2/LLC ATOMIC path (device-coherent by architecture):
//   producer: global_atomic_swap_x2 (atomic 8B publish, no return)
//   consumer: global_atomic_add_x2 +0 with sc0 (atomic coherent 8B read)
// No scope flags to guess, no fallback needed, no fences.
// ---------------------------------------------------------------------------
__global__ __launch_bounds__(256, 1)
__attribute__((amdgpu_waves_per_eu(1, 1)))
void lstm_coop(
    const float* __restrict__ Whh,   // [2048][512]
    const float* __restrict__ xp,    // [nsteps][32][2048]
    float* __restrict__ hx,          // [2][8][2048 granules][2] floats
    float* __restrict__ cbuf,        // [32][512]
    float* __restrict__ out_hs,      // [2048][32][512]
    int t0, int nsteps)
{
    const int w    = blockIdx.x;
    const int g    = w >> 5;         // batch-quad group
    const int sl   = w & 31;         // hid slice [16sl, 16sl+16)
    const int tid  = threadIdx.x;
    const int hw   = tid >> 6;       // wave: hid {4hw..4hw+3} within slice
    const int lane = tid & 63;
    const int rr   = (lane >> 4) & 3;
    const int kg   = lane & 15;      // k-chunk [32kg, 32kg+32)

    __shared__ f32x4 h4[2][512];

    // W rows: 4 gates x hid(16sl+4hw+rr), k-chunk 32 -> 32 x f32x4
    f32x4 wv[32];
#pragma unroll
    for (int gi = 0; gi < 4; ++gi) {
        const float* wr = Whh + (size_t)(512*gi + 16*sl + 4*hw + rr) * 512 + 32*kg;
#pragma unroll
        for (int q = 0; q < 8; ++q) {
            asm volatile("global_load_dwordx4 %0, %1, off"
                         : "=v"(wv[gi*8+q]) : "v"(wr + 4*q));
        }
    }
    asm volatile("s_waitcnt vmcnt(0)" ::: "memory");

    const bool is_tail = ((lane & 12) == 0);   // kg < 4
    const int  jb      = lane & 3;
    const int  hid_gl  = 16*sl + 4*hw + rr;
    const int  b_gl    = 4*g + jb;
    const int  slot_p  = 16*(hid_gl & 31) + (hid_gl >> 5);

    float c_reg = 0.f;
    if (is_tail) c_reg = cbuf[(size_t)b_gl * HID + hid_gl];

    // xp index for this lane's post-butterfly output (gate=kg>>2, b=kg&3)
    const int xrow = 512*(kg >> 2) + 16*sl + 4*hw + rr;
    const int xb   = 4*g + (kg & 3);
    const size_t xoff = (size_t)xb * GATES + xrow;

    float xpv_cur = xp[xoff];   // step t0
    const unsigned long long zr = 0ull;   // atomic-add identity

    for (int t = t0; t < t0 + nsteps; ++t) {
        const int p = t & 1;

        // ---- poll via atomic-unit reads: 8 x (fetch_add 0, sc0 = return old)
        const float* rb = hx + ((size_t)p * 8 + g) * 4096;
        const float* p0 = rb + 8 * tid;
        const float* p1 = rb + 8 * tid + 2048;
        const unsigned tu = __float_as_uint((float)t);
        f32x2 a0, a1, a2, a3, b0, b1, b2, b3;
        while (true) {
            asm volatile(
                "global_atomic_add_x2 %0, %8, %10, off sc0\n\t"
                "global_atomic_add_x2 %1, %8, %10, off offset:8 sc0\n\t"
                "global_atomic_add_x2 %2, %8, %10, off offset:16 sc0\n\t"
                "global_atomic_add_x2 %3, %8, %10, off offset:24 sc0\n\t"
                "global_atomic_add_x2 %4, %9, %10, off sc0\n\t"
                "global_atomic_add_x2 %5, %9, %10, off offset:8 sc0\n\t"
                "global_atomic_add_x2 %6, %9, %10, off offset:16 sc0\n\t"
                "global_atomic_add_x2 %7, %9, %10, off offset:24 sc0\n\t"
                "s_waitcnt vmcnt(0)"
                : "=&v"(a0), "=&v"(a1), "=&v"(a2), "=&v"(a3),
                  "=&v"(b0), "=&v"(b1), "=&v"(b2), "=&v"(b3)
                : "v"(p0), "v"(p1), "v"(zr)
                : "memory");
            if (__float_as_uint(a0[1]) == tu && __float_as_uint(a1[1]) == tu &&
                __float_as_uint(a2[1]) == tu && __float_as_uint(a3[1]) == tu &&
                __float_as_uint(b0[1]) == tu && __float_as_uint(b1[1]) == tu &&
                __float_as_uint(b2[1]) == tu && __float_as_uint(b3[1]) == tu)
                break;
            __builtin_amdgcn_s_sleep(1);
        }

        // prefetch xp for step t+1 (overlaps with dot/butterfly/tail)
        float xpv_next = 0.f;
        if (t + 1 < t0 + nsteps)
            xpv_next = xp[(size_t)(t + 1 - t0) * (BATCH * GATES) + xoff];

        {
            f32x4 v0 = {a0[0], a1[0], a2[0], a3[0]};
            f32x4 v1 = {b0[0], b1[0], b2[0], b3[0]};
            h4[p][tid]       = v0;
            h4[p][tid + 256] = v1;
        }
        __syncthreads();

        // ---- dot: 32 x (b128 broadcast read + 16 FMA), W from regs
        float acc[16];
#pragma unroll
        for (int m = 0; m < 16; ++m) acc[m] = 0.f;
#pragma unroll
        for (int s = 0; s < 32; ++s) {
            f32x4 hv = h4[p][16*s + kg];
#pragma unroll
            for (int gi = 0; gi < 4; ++gi) {
                float wt = wv[gi*8 + (s >> 2)][s & 3];
                acc[4*gi+0] += wt * hv[0];
                acc[4*gi+1] += wt * hv[1];
                acc[4*gi+2] += wt * hv[2];
                acc[4*gi+3] += wt * hv[3];
            }
        }

        // ---- 4-stage index-descending butterfly over kg -> lane kg has acc[kg]
        {
            int sel = (kg >> 3) & 1;
#pragma unroll
            for (int m = 0; m < 8; ++m) {
                float mine = sel ? acc[m+8] : acc[m];
                float send = sel ? acc[m]   : acc[m+8];
                acc[m] = mine + __shfl_xor(send, 8, 64);
            }
        }
        {
            int sel = (kg >> 2) & 1;
#pragma unroll
            for (int m = 0; m < 4; ++m) {
                float mine = sel ? acc[m+4] : acc[m];
                float send = sel ? acc[m]   : acc[m+4];
                acc[m] = mine + __shfl_xor(send, 4, 64);
            }
        }
        {
            int sel = (kg >> 1) & 1;
#pragma unroll
            for (int m = 0; m < 2; ++m) {
                float mine = sel ? acc[m+2] : acc[m];
                float send = sel ? acc[m]   : acc[m+2];
                acc[m] = mine + __shfl_xor(send, 2, 64);
            }
        }
        {
            int sel = kg & 1;
            float mine = sel ? acc[1] : acc[0];
            float send = sel ? acc[0] : acc[1];
            acc[0] = mine + __shfl_xor(send, 1, 64);
        }

        // lane (rr,kg) owns gate kg>>2, batch kg&3, hid 4hw+rr
        float gval = acc[0] + xpv_cur;
        float fv2 = __shfl(gval, (lane & 48) + 4  + jb);
        float gv2 = __shfl(gval, (lane & 48) + 8  + jb);
        float ov2 = __shfl(gval, (lane & 48) + 12 + jb);

        if (is_tail) {
            float iv = fsigmoid(gval);
            float fv = fsigmoid(fv2);
            float gv = ftanh(gv2);
            float ov = fsigmoid(ov2);
            float cn = fv * c_reg + iv * gv;
            float hn = ov * ftanh(cn);
            c_reg = cn;
            f32x2 pkt;
            pkt[0] = hn;
            pkt[1] = (float)(t + 1);
            float* wp = hx + ((size_t)((t + 1) & 1) * 8 + g) * 4096
                        + 8 * slot_p + 2 * jb;
            // atomic 8B publish (device-coherent, data+tag in one op)
            asm volatile("global_atomic_swap_x2 %0, %1, off"
                         :: "v"(wp), "v"(pkt) : "memory");
            // off-critical-path output store
            out_hs[(size_t)t * (BATCH * HID) + (size_t)b_gl * HID + hid_gl] = hn;
        }
        xpv_cur = xpv_next;
    }

    if (is_tail) cbuf[(size_t)b_gl * HID + hid_gl] = c_reg;
}

// ---------------------------------------------------------------------------
__global__ void init_kernel(const float* __restrict__ h0,
                            const float* __restrict__ c0,
                            float* __restrict__ hx,
                            float* __restrict__ cbuf)
{
    int idx = blockIdx.x * 256 + threadIdx.x;
    if (idx < 16384) {
        int g = idx >> 11, G = idx & 2047;
        int slot = G >> 2, c = G & 3;
        int k = 32 * (slot & 15) + (slot >> 4);
        int b = 4 * g + c;
        // parity 0: h0 with tag 0
        hx[(size_t)g * 4096 + 2*G]     = h0[(size_t)b * HID + k];
        hx[(size_t)g * 4096 + 2*G + 1] = 0.0f;
        // parity 1: invalid tag (NaN bits -> never equals any (float)t)
        hx[(size_t)32768 + (size_t)g * 4096 + 2*G]     = 0.0f;
        hx[(size_t)32768 + (size_t)g * 4096 + 2*G + 1] = __uint_as_float(0xFFFFFFFFu);
        cbuf[idx] = c0[idx];
    }
}

__global__ void tail_kernel(const float* __restrict__ hx,   // parity 0 = h_SEQ
                            const float* __restrict__ cbuf,
                            float* __restrict__ out)
{
    int idx = blockIdx.x * 256 + threadIdx.x;
    if (idx < BATCH * HID) {
        int b = idx >> 9, k = idx & 511;
        int g = b >> 2, c = b & 3;
        int slot = 16 * (k & 31) + (k >> 5);
        int G = 4 * slot + c;
        out[(size_t)SEQ * BATCH * HID + idx] = hx[(size_t)g * 4096 + 2*G];
        out[(size_t)SEQ * BATCH * HID + BATCH * HID + idx] = cbuf[idx];
    }
}

// ---------------------------------------------------------------------------
extern "C" void kernel_launch(void* const* d_in, const int* in_sizes, int n_in,
                              void* d_out, int out_size, void* d_ws, size_t ws_size,
                              hipStream_t stream)
{
    const float* x   = (const float*)d_in[0];
    const float* h0  = (const float*)d_in[1];
    const float* c0  = (const float*)d_in[2];
    const float* Wih = (const float*)d_in[3];
    const float* Whh = (const float*)d_in[4];
    const float* bih = (const float*)d_in[5];
    const float* bhh = (const float*)d_in[6];
    float* out = (float*)d_out;

    float* hx   = (float*)d_ws;              // 65536 floats (2x8x2048x2)
    float* cbuf = hx + 65536;                // 16384 floats
    float* xp   = cbuf + 16384;
    size_t used_floats = 65536 + 16384;
    size_t avail = (ws_size / 4 > used_floats) ? (ws_size / 4 - used_floats) : 0;
    int chunk = (int)(avail / (size_t)(BATCH * GATES));
    if (chunk > SEQ) chunk = SEQ;
    chunk &= ~3;
    if (chunk < 4) chunk = 4;

    hipLaunchKernelGGL(init_kernel, dim3(64), dim3(256), 0, stream,
                       h0, c0, hx, cbuf);

    for (int t0 = 0; t0 < SEQ; t0 += chunk) {
        int n = SEQ - t0; if (n > chunk) n = chunk;
        int M = n * BATCH;
        hipLaunchKernelGGL(xproj_kernel, dim3(16 * (M / 128)), dim3(256), 0, stream,
                           x + (size_t)t0 * BATCH * IN_DIM, Wih, bih, bhh, xp, M);

        const float* xp_c = xp;
        int t0_arg = t0, n_arg = n;
        void* args[] = { (void*)&Whh, (void*)&xp_c, (void*)&hx, (void*)&cbuf,
                         (void*)&out, (void*)&t0_arg, (void*)&n_arg };
        hipLaunchCooperativeKernel((void*)lstm_coop, dim3(256), dim3(256),
                                   args, 0, stream);
    }

    hipLaunchKernelGGL(tail_kernel, dim3(64), dim3(256), 0, stream,
                       hx, cbuf, out);
}

// Round 9
// 17861.420 us; speedup vs baseline: 2.1219x; 2.1219x over previous
//
#include <hip/hip_runtime.h>
#include <math.h>

#define SEQ    2048
#define BATCH  32
#define IN_DIM 512
#define HID    512
#define GATES  2048
#define NSCAN  16
#define NWG    256

typedef __attribute__((ext_vector_type(4))) float        f32x4;
typedef __attribute__((ext_vector_type(4))) unsigned int u32x4;
typedef __attribute__((ext_vector_type(8))) short        s16x8;

__device__ inline float fsigmoid(float x){ return 1.f/(1.f+__expf(-x)); }
__device__ inline float ftanh(float x){ return 1.f - 2.f/(1.f+__expf(2.f*x)); }
__device__ inline unsigned short f2bf(float f){
    unsigned u = __float_as_uint(f);
    u = (u + 0x7FFFu + ((u>>16)&1u)) >> 16;
    return (unsigned short)u;
}
__device__ inline float bf2f(unsigned short h){ return __uint_as_float(((unsigned)h)<<16); }
// LDS bank swizzle for [32 batch][512 k] bf16 regions (1024 B rows)
__device__ inline unsigned swz(unsigned b){ return b ^ ((((b>>10)^(b>>7))&7u)<<4); }

#define MFMA(A,B,C) __builtin_amdgcn_mfma_f32_16x16x32_bf16(A,B,C,0,0,0)

// ---------------------------------------------------------------------------
// init: publish h0 (split-bf16, parity 0, tags=0), invalidate parity-1 tags,
// zero tile counters and progress word. Runs every launch (replay-safe).
// ---------------------------------------------------------------------------
__global__ void init_kernel(const float* __restrict__ h0,
                            unsigned short* __restrict__ Hhi,
                            unsigned short* __restrict__ Hlo,
                            unsigned* __restrict__ tags,
                            unsigned* __restrict__ cnt)   // cnt[SEQ+4]; P = cnt[SEQ]
{
    int idx = blockIdx.x*256 + threadIdx.x;
    if (idx < BATCH*HID) {
        float f = h0[idx];
        unsigned short hh = f2bf(f);
        Hhi[idx] = hh;
        Hlo[idx] = f2bf(f - bf2f(hh));
    }
    if (idx < 16) tags[idx*4] = 0u;
    else if (idx < 32) tags[64 + (idx-16)*4] = 0xFFFFFFFFu;
    if (idx < SEQ+4) cnt[idx] = 0u;
}

// ---------------------------------------------------------------------------
// Scan role: 16 WGs, all 32 batches, whole W_hh in register fragments.
// Wave ww owns M-tiles {2ww,2ww+1} of the row'=4*hid+gate x k GEMM.
// Per step: poll(tags==t, cnt[t]==16) -> one batched sc0sc1 load of
// Hhi/Hlo (64KB total across WG) + xp -> swizzled LDS stage -> 192 MFMA ->
// per-lane LSTM cell (4 gates in the 4 C regs) -> split-bf16 publish -> tag.
// ---------------------------------------------------------------------------
__device__ __forceinline__ void scan_role(
    const float* __restrict__ Whh, const float* __restrict__ c0in,
    const float* __restrict__ xpring, int Rmask,
    unsigned short* __restrict__ Hhi, unsigned short* __restrict__ Hlo,
    unsigned* __restrict__ tags, unsigned* __restrict__ cnt,
    unsigned* __restrict__ Pw,
    float* __restrict__ out, unsigned* smem)
{
    const int w    = blockIdx.x;
    const int tid  = threadIdx.x;
    const int lane = tid & 63, hw = tid >> 6;
    const int ww   = w*4 + hw;
    const int lm   = lane & 15, lk = lane >> 4;

    // ---- W_hh fragments: 2 M-tiles x 16 K-steps x {hi,lo} = 256 regs
    s16x8 wfh[2][16], wfl[2][16];
#pragma unroll
    for (int mt = 0; mt < 2; ++mt) {
        const int rowp = (2*ww+mt)*16 + lm;              // row' = 4*hid+gate
        const int wrow = ((rowp & 3) << 9) | (rowp >> 2); // 512*gate + hid
        const float* wb = Whh + (size_t)wrow*512;
#pragma unroll
        for (int ks = 0; ks < 16; ++ks) {
            const float* s = wb + ks*32 + lk*8;
            s16x8 hi, lo;
#pragma unroll
            for (int e = 0; e < 8; ++e) {
                float f = s[e];
                unsigned short h = f2bf(f);
                hi[e] = (short)h;
                lo[e] = (short)f2bf(f - bf2f(h));
            }
            wfh[mt][ks] = hi; wfl[mt][ks] = lo;
        }
    }

    const int hidA = (2*ww)*4 + lk, hidB = (2*ww+1)*4 + lk;
    const int batA = lm,            batB = 16 + lm;

    float c00 = c0in[batA*512 + hidA];
    float c01 = c0in[batB*512 + hidA];
    float c10 = c0in[batA*512 + hidB];
    float c11 = c0in[batB*512 + hidB];

    char* hib = (char*)smem;          // 32 KB swizzled [32][512] bf16 (hi)
    char* lob = hib + 32768;          // 32 KB (lo)

    for (int t = 0; t < SEQ; ++t) {
        const int p = t & 1;
        // ---- poll: 15 peer tags + xp tile counter
        {
            const unsigned tu = (unsigned)t;
            const bool istag = (lane < 16) && (lane != w);
            const unsigned* pp = istag ? (tags + p*64 + lane*4) : (cnt + t);
            while (1) {
                unsigned v;
                asm volatile("global_load_dword %0, %1, off sc0 sc1\n\t"
                             "s_waitcnt vmcnt(0)"
                             : "=&v"(v) : "v"(pp) : "memory");
                bool bad = istag ? (v != tu) : (v < 16u);
                if (__ballot(bad) == 0ull) break;
                __builtin_amdgcn_s_sleep(1);
            }
        }
        // ---- single batched load: h hi/lo (128B each) + xp (4x16B)
        const unsigned short* hp = Hhi + p*16384 + tid*64;
        const unsigned short* lp = Hlo + p*16384 + tid*64;
        const float* xpr = xpring + (size_t)(t & Rmask)*65536;
        const float* xA0 = xpr + batA*2048 + 4*hidA;
        const float* xB0 = xpr + batB*2048 + 4*hidA;
        const float* xA1 = xpr + batA*2048 + 4*hidB;
        const float* xB1 = xpr + batB*2048 + 4*hidB;
        u32x4 hv0,hv1,hv2,hv3,hv4,hv5,hv6,hv7;
        u32x4 lv0,lv1,lv2,lv3,lv4,lv5,lv6,lv7;
        f32x4 x00,x01,x10,x11;
        asm volatile(
            "global_load_dwordx4 %0,  %20, off sc0 sc1\n\t"
            "global_load_dwordx4 %1,  %20, off offset:16 sc0 sc1\n\t"
            "global_load_dwordx4 %2,  %20, off offset:32 sc0 sc1\n\t"
            "global_load_dwordx4 %3,  %20, off offset:48 sc0 sc1\n\t"
            "global_load_dwordx4 %4,  %20, off offset:64 sc0 sc1\n\t"
            "global_load_dwordx4 %5,  %20, off offset:80 sc0 sc1\n\t"
            "global_load_dwordx4 %6,  %20, off offset:96 sc0 sc1\n\t"
            "global_load_dwordx4 %7,  %20, off offset:112 sc0 sc1\n\t"
            "global_load_dwordx4 %8,  %21, off sc0 sc1\n\t"
            "global_load_dwordx4 %9,  %21, off offset:16 sc0 sc1\n\t"
            "global_load_dwordx4 %10, %21, off offset:32 sc0 sc1\n\t"
            "global_load_dwordx4 %11, %21, off offset:48 sc0 sc1\n\t"
            "global_load_dwordx4 %12, %21, off offset:64 sc0 sc1\n\t"
            "global_load_dwordx4 %13, %21, off offset:80 sc0 sc1\n\t"
            "global_load_dwordx4 %14, %21, off offset:96 sc0 sc1\n\t"
            "global_load_dwordx4 %15, %21, off offset:112 sc0 sc1\n\t"
            "global_load_dwordx4 %16, %22, off sc0 sc1\n\t"
            "global_load_dwordx4 %17, %23, off sc0 sc1\n\t"
            "global_load_dwordx4 %18, %24, off sc0 sc1\n\t"
            "global_load_dwordx4 %19, %25, off sc0 sc1\n\t"
            "s_waitcnt vmcnt(0)"
            : "=&v"(hv0),"=&v"(hv1),"=&v"(hv2),"=&v"(hv3),
              "=&v"(hv4),"=&v"(hv5),"=&v"(hv6),"=&v"(hv7),
              "=&v"(lv0),"=&v"(lv1),"=&v"(lv2),"=&v"(lv3),
              "=&v"(lv4),"=&v"(lv5),"=&v"(lv6),"=&v"(lv7),
              "=&v"(x00),"=&v"(x01),"=&v"(x10),"=&v"(x11)
            : "v"(hp), "v"(lp), "v"(xA0), "v"(xB0), "v"(xA1), "v"(xB1)
            : "memory");
        // ---- stage to LDS (swizzled, even 8-lane/quad spread)
        {
            unsigned bb = (unsigned)tid*128u;
            *(u32x4*)(hib + swz(bb+  0)) = hv0;
            *(u32x4*)(hib + swz(bb+ 16)) = hv1;
            *(u32x4*)(hib + swz(bb+ 32)) = hv2;
            *(u32x4*)(hib + swz(bb+ 48)) = hv3;
            *(u32x4*)(hib + swz(bb+ 64)) = hv4;
            *(u32x4*)(hib + swz(bb+ 80)) = hv5;
            *(u32x4*)(hib + swz(bb+ 96)) = hv6;
            *(u32x4*)(hib + swz(bb+112)) = hv7;
            *(u32x4*)(lob + swz(bb+  0)) = lv0;
            *(u32x4*)(lob + swz(bb+ 16)) = lv1;
            *(u32x4*)(lob + swz(bb+ 32)) = lv2;
            *(u32x4*)(lob + swz(bb+ 48)) = lv3;
            *(u32x4*)(lob + swz(bb+ 64)) = lv4;
            *(u32x4*)(lob + swz(bb+ 80)) = lv5;
            *(u32x4*)(lob + swz(bb+ 96)) = lv6;
            *(u32x4*)(lob + swz(bb+112)) = lv7;
        }
        __syncthreads();

        // ---- 192 MFMA: D = W(2 M-tiles) x h(2 N-tiles), 3-term split-bf16
        f32x4 a00 = {0.f,0.f,0.f,0.f}, a01 = a00, a10 = a00, a11 = a00;
#pragma unroll
        for (int ks = 0; ks < 16; ++ks) {
            unsigned o0 = ((unsigned)batA<<10) + (unsigned)(ks*64 + lk*16);
            unsigned o1 = ((unsigned)batB<<10) + (unsigned)(ks*64 + lk*16);
            s16x8 bh0 = *(const s16x8*)(hib + swz(o0));
            s16x8 bl0 = *(const s16x8*)(lob + swz(o0));
            s16x8 bh1 = *(const s16x8*)(hib + swz(o1));
            s16x8 bl1 = *(const s16x8*)(lob + swz(o1));
            a00 = MFMA(wfh[0][ks], bh0, a00);
            a00 = MFMA(wfh[0][ks], bl0, a00);
            a00 = MFMA(wfl[0][ks], bh0, a00);
            a01 = MFMA(wfh[0][ks], bh1, a01);
            a01 = MFMA(wfh[0][ks], bl1, a01);
            a01 = MFMA(wfl[0][ks], bh1, a01);
            a10 = MFMA(wfh[1][ks], bh0, a10);
            a10 = MFMA(wfh[1][ks], bl0, a10);
            a10 = MFMA(wfl[1][ks], bh0, a10);
            a11 = MFMA(wfh[1][ks], bh1, a11);
            a11 = MFMA(wfh[1][ks], bl1, a11);
            a11 = MFMA(wfl[1][ks], bh1, a11);
        }

        // ---- per-lane LSTM cell: C regs = {i,f,g,o} of one (hid,batch)
        unsigned short* Hh1 = Hhi + ((t+1)&1)*16384;
        unsigned short* Hl1 = Hlo + ((t+1)&1)*16384;
        float* outT = out + (size_t)t*16384;

#define CELL(ACC, XPV, CS, BAT, HIDX)                                         \
        {                                                                     \
            float gi = ACC[0] + XPV[0];                                       \
            float gf = ACC[1] + XPV[1];                                       \
            float gg = ACC[2] + XPV[2];                                       \
            float go = ACC[3] + XPV[3];                                       \
            float iv = fsigmoid(gi), fv = fsigmoid(gf);                       \
            float gv = ftanh(gg),    ov = fsigmoid(go);                       \
            float cn = fv*CS + iv*gv;                                         \
            float hn = ov*ftanh(cn);                                          \
            CS = cn;                                                          \
            unsigned short hh = f2bf(hn);                                     \
            unsigned short hl = f2bf(hn - bf2f(hh));                          \
            unsigned short* ph = Hh1 + (BAT)*512 + (HIDX);                    \
            unsigned short* pl = Hl1 + (BAT)*512 + (HIDX);                    \
            asm volatile("global_store_short %0, %1, off sc0 sc1"             \
                         :: "v"(ph), "v"((unsigned)hh) : "memory");           \
            asm volatile("global_store_short %0, %1, off sc0 sc1"             \
                         :: "v"(pl), "v"((unsigned)hl) : "memory");           \
            outT[(BAT)*512 + (HIDX)] = hn;                                    \
            if (t == SEQ-1)                                                   \
                out[(size_t)SEQ*16384 + (BAT)*512 + (HIDX)] = hn;             \
        }
        CELL(a00, x00, c00, batA, hidA)
        CELL(a01, x01, c01, batB, hidA)
        CELL(a10, x10, c10, batA, hidB)
        CELL(a11, x11, c11, batB, hidB)
#undef CELL

        __syncthreads();   // drains publish stores (vmcnt) across all waves
        if (tid == 0) {
            unsigned tv = (unsigned)(t + 1);
            unsigned* tp = tags + ((t+1)&1)*64 + w*4;
            asm volatile("global_store_dword %0, %1, off sc0 sc1"
                         :: "v"(tp), "v"(tv) : "memory");
            if (w == 0)
                asm volatile("global_store_dword %0, %1, off sc0 sc1"
                             :: "v"(Pw), "v"(tv) : "memory");
        }
    }

    // final c state
    float* cT = out + (size_t)SEQ*16384 + 16384;
    cT[batA*512 + hidA] = c00;
    cT[batB*512 + hidA] = c01;
    cT[batA*512 + hidB] = c10;
    cT[batB*512 + hidB] = c11;
}

// ---------------------------------------------------------------------------
// xproj role: 240 WGs stream tiles (t, nb): 32 batches x 128 row' cols,
// K=512, into the xp ring (row' = 4*hid+gate permuted layout, bias folded).
// Ring slot reuse gated by scan progress word P.
// ---------------------------------------------------------------------------
__device__ __forceinline__ void xproj_role(
    const float* __restrict__ x, const float* __restrict__ Wih,
    const float* __restrict__ bih, const float* __restrict__ bhh,
    float* __restrict__ xpring, int R, int Rmask,
    unsigned* __restrict__ cnt, const unsigned* __restrict__ Pw,
    unsigned* smem)
{
    const int j   = blockIdx.x - NSCAN;
    const int tid = threadIdx.x;
    float* As = (float*)smem;          // [16][33]
    float* Bs = As + 16*33;            // [16][132]
    const int tx = tid & 15, ty = tid >> 4;

    for (int tau = j; tau < SEQ*16; tau += (NWG - NSCAN)) {
        const int t = tau >> 4, nb = tau & 15, n0 = nb*128;
        // ring gate
        const int tneed = t - R + 2;
        if (tneed > 0) {
            while (1) {
                unsigned pv;
                asm volatile("global_load_dword %0, %1, off sc0 sc1\n\t"
                             "s_waitcnt vmcnt(0)"
                             : "=&v"(pv) : "v"(Pw) : "memory");
                if ((int)pv >= tneed) break;
                __builtin_amdgcn_s_sleep(32);
            }
        }
        // biases for this thread's 8 columns
        float bj[8];
#pragma unroll
        for (int q = 0; q < 8; ++q) {
            int rowp = n0 + 8*ty + q;
            int wr = ((rowp & 3) << 9) | (rowp >> 2);
            bj[q] = bih[wr] + bhh[wr];
        }
        float acc[2][8];
#pragma unroll
        for (int i = 0; i < 2; ++i)
#pragma unroll
            for (int q = 0; q < 8; ++q) acc[i][q] = 0.f;

        for (int kc = 0; kc < 512; kc += 16) {
            if (tid < 128) {
                int r = tid >> 2, u = tid & 3;
                f32x4 v = *(const f32x4*)(x + ((size_t)t*32 + r)*512 + kc + 4*u);
                As[(4*u+0)*33 + r] = v[0];
                As[(4*u+1)*33 + r] = v[1];
                As[(4*u+2)*33 + r] = v[2];
                As[(4*u+3)*33 + r] = v[3];
            }
#pragma unroll
            for (int h2 = 0; h2 < 2; ++h2) {
                int idx = tid*2 + h2;
                int r = idx >> 2, u = idx & 3;
                int rowp = n0 + r;
                int wr = ((rowp & 3) << 9) | (rowp >> 2);
                f32x4 v = *(const f32x4*)(Wih + (size_t)wr*512 + kc + 4*u);
                Bs[(4*u+0)*132 + r] = v[0];
                Bs[(4*u+1)*132 + r] = v[1];
                Bs[(4*u+2)*132 + r] = v[2];
                Bs[(4*u+3)*132 + r] = v[3];
            }
            __syncthreads();
#pragma unroll
            for (int kk = 0; kk < 16; ++kk) {
                float a0 = As[kk*33 + 2*tx];
                float a1 = As[kk*33 + 2*tx + 1];
                f32x4 b0 = *(const f32x4*)(Bs + kk*132 + 8*ty);
                f32x4 b1 = *(const f32x4*)(Bs + kk*132 + 8*ty + 4);
#pragma unroll
                for (int q = 0; q < 4; ++q) {
                    acc[0][q]   += a0 * b0[q];
                    acc[0][q+4] += a0 * b1[q];
                    acc[1][q]   += a1 * b0[q];
                    acc[1][q+4] += a1 * b1[q];
                }
            }
            __syncthreads();
        }
        // store (sc0 sc1 write-through so scan's bypassing loads see it)
        float* dst = xpring + (size_t)(t & Rmask)*65536;
#pragma unroll
        for (int i = 0; i < 2; ++i) {
            int m = 2*tx + i;
            f32x4 v0 = {acc[i][0]+bj[0], acc[i][1]+bj[1],
                        acc[i][2]+bj[2], acc[i][3]+bj[3]};
            f32x4 v1 = {acc[i][4]+bj[4], acc[i][5]+bj[5],
                        acc[i][6]+bj[6], acc[i][7]+bj[7]};
            float* pp = dst + (size_t)m*2048 + n0 + 8*ty;
            asm volatile("global_store_dwordx4 %0, %1, off sc0 sc1"
                         :: "v"(pp), "v"(v0) : "memory");
            asm volatile("global_store_dwordx4 %0, %1, off sc0 sc1"
                         :: "v"(pp+4), "v"(v1) : "memory");
        }
        __syncthreads();                 // drain stores (vmcnt) in all waves
        if (tid == 0) atomicAdd(cnt + t, 1u);
    }
}

// ---------------------------------------------------------------------------
__global__ __launch_bounds__(256, 1)
__attribute__((amdgpu_waves_per_eu(1, 1)))
void fused_kernel(const float* __restrict__ x,
                  const float* __restrict__ c0,
                  const float* __restrict__ Wih,
                  const float* __restrict__ Whh,
                  const float* __restrict__ bih,
                  const float* __restrict__ bhh,
                  float* __restrict__ out,
                  unsigned short* __restrict__ Hhi,
                  unsigned short* __restrict__ Hlo,
                  unsigned* __restrict__ tags,
                  unsigned* __restrict__ cnt,
                  float* __restrict__ xpring,
                  int R)
{
    __shared__ unsigned smem[16384];   // 64 KB: scan h-stage / xproj tiles
    unsigned* Pw = cnt + SEQ;
    if (blockIdx.x < NSCAN)
        scan_role(Whh, c0, xpring, R-1, Hhi, Hlo, tags, cnt, Pw, out, smem);
    else
        xproj_role(x, Wih, bih, bhh, xpring, R, R-1, cnt, Pw, smem);
}

// ---------------------------------------------------------------------------
extern "C" void kernel_launch(void* const* d_in, const int* in_sizes, int n_in,
                              void* d_out, int out_size, void* d_ws, size_t ws_size,
                              hipStream_t stream)
{
    const float* x   = (const float*)d_in[0];
    const float* h0  = (const float*)d_in[1];
    const float* c0  = (const float*)d_in[2];
    const float* Wih = (const float*)d_in[3];
    const float* Whh = (const float*)d_in[4];
    const float* bih = (const float*)d_in[5];
    const float* bhh = (const float*)d_in[6];
    float* out = (float*)d_out;

    char* base = (char*)d_ws;
    unsigned short* Hhi  = (unsigned short*)base;             // 64 KB (2 parities)
    unsigned short* Hlo  = (unsigned short*)(base + 65536);   // 64 KB
    unsigned*       tags = (unsigned*)(base + 131072);        // 512 B
    unsigned*       cnt  = (unsigned*)(base + 131584);        // (SEQ+4)*4
    size_t ringoff = (size_t)(131584 + (SEQ+4)*4 + 255) & ~(size_t)255;
    float* xpring = (float*)(base + ringoff);

    size_t avail = (ws_size > ringoff) ? ws_size - ringoff : 0;
    long long Rll = (long long)(avail / (65536ull*4ull));
    int R = (Rll > 256) ? 256 : (int)Rll;
    while (R & (R-1)) R &= R-1;   // pow2 floor
    if (R < 2) R = 2;

    hipLaunchKernelGGL(init_kernel, dim3(64), dim3(256), 0, stream,
                       h0, Hhi, Hlo, tags, cnt);
    hipLaunchKernelGGL(fused_kernel, dim3(NWG), dim3(256), 0, stream,
                       x, c0, Wih, Whh, bih, bhh, out,
                       Hhi, Hlo, tags, cnt, xpring, R);
}

// Round 10
// 13932.356 us; speedup vs baseline: 2.7203x; 1.2820x over previous
//
#include <hip/hip_runtime.h>
#include <math.h>

#define SEQ    2048
#define BATCH  32
#define IN_DIM 512
#define HID    512
#define GATES  2048
#define NSCAN  32
#define NWG    256

typedef __attribute__((ext_vector_type(4))) float        f32x4;
typedef __attribute__((ext_vector_type(4))) unsigned int u32x4;
typedef __attribute__((ext_vector_type(2))) unsigned int u32x2;
typedef __attribute__((ext_vector_type(8))) short        s16x8;

__device__ inline float fsigmoid(float x){ return 1.f/(1.f+__expf(-x)); }
__device__ inline float ftanh(float x){ return 1.f - 2.f/(1.f+__expf(2.f*x)); }
__device__ inline unsigned f2bf(float f){
    unsigned u = __float_as_uint(f);
    return (u + 0x7FFFu + ((u>>16)&1u)) >> 16;
}
__device__ inline float bf2f(unsigned h){ return __uint_as_float(h<<16); }

#define MFMA(A,B,C) __builtin_amdgcn_mfma_f32_16x16x32_bf16(A,B,C,0,0,0)

// ---------------------------------------------------------------------------
// init: h0 -> split-bf16 [bat][hid] parity 0; tags/cnt/P zero. Replay-safe.
// ---------------------------------------------------------------------------
__global__ void init_kernel(const float* __restrict__ h0,
                            unsigned short* __restrict__ Hhi,
                            unsigned short* __restrict__ Hlo,
                            unsigned* __restrict__ tags,   // [32]
                            unsigned* __restrict__ cnt)    // [SEQ+4]; P=cnt[SEQ]
{
    int idx = blockIdx.x*256 + threadIdx.x;
    if (idx < BATCH*HID) {
        float f = h0[idx];
        unsigned hh = f2bf(f);
        Hhi[idx] = (unsigned short)hh;
        Hlo[idx] = (unsigned short)f2bf(f - bf2f(hh));
    }
    if (idx < 32) tags[idx] = 0u;
    if (idx < SEQ+4) cnt[idx] = 0u;
}

// ---------------------------------------------------------------------------
// Scan role: 32 WGs x 4 waves; wave W in [0,128) owns M-tile W (16 rows' =
// 4 hid x 4 gates), all 32 batches. W_hh split-bf16 A-frags in 128 VGPRs.
// ---------------------------------------------------------------------------
__device__ __forceinline__ void scan_role(
    const float* __restrict__ Whh, const float* __restrict__ c0in,
    const float* __restrict__ xpring, int Rmask,
    unsigned short* __restrict__ Hhi, unsigned short* __restrict__ Hlo,
    unsigned* __restrict__ tags, unsigned* __restrict__ cnt,
    float* __restrict__ out, char* lds)
{
    const int w = blockIdx.x, tid = threadIdx.x;
    const int hw = tid>>6, lane = tid&63;
    const int lm = lane&15, lk = lane>>4;
    const int W = w*4 + hw;

    // ---- W_hh A-fragments (hi/lo), 32 x s16x8 = 128 regs
    s16x8 wfh[16], wfl[16];
    {
        int rowp = W*16 + lm;                       // row' = 4*hid+gate
        int wrow = ((rowp&3)<<9) | (rowp>>2);       // 512*gate + hid
        const float* wb = Whh + (size_t)wrow*512;
#pragma unroll
        for (int ks=0; ks<16; ++ks){
            const float* s = wb + ks*32 + lk*8;
            s16x8 hi, lo;
#pragma unroll
            for (int e=0;e<8;++e){
                float f = s[e];
                unsigned h = f2bf(f);
                hi[e] = (short)h;
                lo[e] = (short)f2bf(f - bf2f(h));
            }
            wfh[ks]=hi; wfl[ks]=lo;
        }
    }

    const int hid  = 4*W + lk;
    const int batA = lm, batB = 16 + lm;
    float cA = c0in[(size_t)batA*HID + hid];
    float cB = c0in[(size_t)batB*HID + hid];

    // LDS write addrs: linear byte b = tid*128 + j*16, swz: b ^= ((b>>10)&7)<<4
    unsigned wa[8];
    {
        unsigned xv = (((unsigned)(tid>>3))&7u)<<4;
#pragma unroll
        for (int j=0;j<8;++j)
            wa[j] = (unsigned)tid*128u + (((unsigned)j*16u) ^ xv);
    }
    // LDS read bases (even/odd ks), same swizzle; lo region = +32768 imm
    unsigned rA0, rA1, rB0, rB1;
    {
        unsigned xA = ((unsigned)(batA&7))<<4, xB = ((unsigned)(batB&7))<<4;
        unsigned bA = (unsigned)batA*1024u + (unsigned)lk*16u;
        unsigned bB = (unsigned)batB*1024u + (unsigned)lk*16u;
        rA0 = bA ^ xA; rA1 = (bA + 64u) ^ xA;
        rB0 = bB ^ xB; rB1 = (bB + 64u) ^ xB;
    }

    for (int t=0; t<SEQ; ++t){
        const int p = t & 1;
        // ---- poll: 32 WG tags + xp tile counter, one RT per iteration
        {
            const unsigned* tp = tags + (lane & 31);
            const unsigned* cp = cnt + t;
            while (1){
                unsigned tv, cv;
                asm volatile(
                    "global_load_dword %0, %2, off sc0 sc1\n\t"
                    "global_load_dword %1, %3, off sc0 sc1\n\t"
                    "s_waitcnt vmcnt(0)"
                    : "=&v"(tv), "=&v"(cv) : "v"(tp), "v"(cp) : "memory");
                bool bad = (tv < (unsigned)t) | (cv < 16u);
                if (__ballot(bad) == 0ull) break;
                __builtin_amdgcn_s_sleep(1);
            }
        }
        // ---- stage h(t) hi/lo (128B each) + xp (2x16B): 18 loads, one drain
        const unsigned short* hp = Hhi + (size_t)p*16384 + tid*64;
        const unsigned short* lp = Hlo + (size_t)p*16384 + tid*64;
        const float* xpr = xpring + (size_t)(t & Rmask)*65536;
        const float* xa = xpr + (size_t)batA*2048 + 16*W + 4*lk;
        const float* xb = xpr + (size_t)batB*2048 + 16*W + 4*lk;
        u32x4 h0,h1,h2,h3,h4,h5,h6,h7, l0,l1,l2,l3,l4,l5,l6,l7;
        f32x4 xva, xvb;
        asm volatile(
            "global_load_dwordx4 %0,  %18, off sc0 sc1\n\t"
            "global_load_dwordx4 %1,  %18, off offset:16 sc0 sc1\n\t"
            "global_load_dwordx4 %2,  %18, off offset:32 sc0 sc1\n\t"
            "global_load_dwordx4 %3,  %18, off offset:48 sc0 sc1\n\t"
            "global_load_dwordx4 %4,  %18, off offset:64 sc0 sc1\n\t"
            "global_load_dwordx4 %5,  %18, off offset:80 sc0 sc1\n\t"
            "global_load_dwordx4 %6,  %18, off offset:96 sc0 sc1\n\t"
            "global_load_dwordx4 %7,  %18, off offset:112 sc0 sc1\n\t"
            "global_load_dwordx4 %8,  %19, off sc0 sc1\n\t"
            "global_load_dwordx4 %9,  %19, off offset:16 sc0 sc1\n\t"
            "global_load_dwordx4 %10, %19, off offset:32 sc0 sc1\n\t"
            "global_load_dwordx4 %11, %19, off offset:48 sc0 sc1\n\t"
            "global_load_dwordx4 %12, %19, off offset:64 sc0 sc1\n\t"
            "global_load_dwordx4 %13, %19, off offset:80 sc0 sc1\n\t"
            "global_load_dwordx4 %14, %19, off offset:96 sc0 sc1\n\t"
            "global_load_dwordx4 %15, %19, off offset:112 sc0 sc1\n\t"
            "global_load_dwordx4 %16, %20, off sc0 sc1\n\t"
            "global_load_dwordx4 %17, %21, off sc0 sc1\n\t"
            "s_waitcnt vmcnt(0)"
            : "=&v"(h0),"=&v"(h1),"=&v"(h2),"=&v"(h3),
              "=&v"(h4),"=&v"(h5),"=&v"(h6),"=&v"(h7),
              "=&v"(l0),"=&v"(l1),"=&v"(l2),"=&v"(l3),
              "=&v"(l4),"=&v"(l5),"=&v"(l6),"=&v"(l7),
              "=&v"(xva),"=&v"(xvb)
            : "v"(hp), "v"(lp), "v"(xa), "v"(xb)
            : "memory");
        *(u32x4*)(lds + wa[0]) = h0;  *(u32x4*)(lds + wa[0] + 32768) = l0;
        *(u32x4*)(lds + wa[1]) = h1;  *(u32x4*)(lds + wa[1] + 32768) = l1;
        *(u32x4*)(lds + wa[2]) = h2;  *(u32x4*)(lds + wa[2] + 32768) = l2;
        *(u32x4*)(lds + wa[3]) = h3;  *(u32x4*)(lds + wa[3] + 32768) = l3;
        *(u32x4*)(lds + wa[4]) = h4;  *(u32x4*)(lds + wa[4] + 32768) = l4;
        *(u32x4*)(lds + wa[5]) = h5;  *(u32x4*)(lds + wa[5] + 32768) = l5;
        *(u32x4*)(lds + wa[6]) = h6;  *(u32x4*)(lds + wa[6] + 32768) = l6;
        *(u32x4*)(lds + wa[7]) = h7;  *(u32x4*)(lds + wa[7] + 32768) = l7;
        __syncthreads();

        // ---- 96 MFMA: 16 ks x {1 Mtile x 2 Ntiles x 3 split terms}
        f32x4 aA0={0.f,0.f,0.f,0.f}, aA1=aA0, aB0=aA0, aB1=aA0;
#pragma unroll
        for (int ks=0; ks<16; ++ks){
            const char* pA = lds + ((ks&1)? rA1 : rA0) + (ks>>1)*128;
            const char* pB = lds + ((ks&1)? rB1 : rB0) + (ks>>1)*128;
            s16x8 bhA = *(const s16x8*)pA;
            s16x8 blA = *(const s16x8*)(pA + 32768);
            s16x8 bhB = *(const s16x8*)pB;
            s16x8 blB = *(const s16x8*)(pB + 32768);
            if (ks & 1){
                aA1 = MFMA(wfh[ks], bhA, aA1);
                aA1 = MFMA(wfh[ks], blA, aA1);
                aA1 = MFMA(wfl[ks], bhA, aA1);
                aB1 = MFMA(wfh[ks], bhB, aB1);
                aB1 = MFMA(wfh[ks], blB, aB1);
                aB1 = MFMA(wfl[ks], bhB, aB1);
            } else {
                aA0 = MFMA(wfh[ks], bhA, aA0);
                aA0 = MFMA(wfh[ks], blA, aA0);
                aA0 = MFMA(wfl[ks], bhA, aA0);
                aB0 = MFMA(wfh[ks], bhB, aB0);
                aB0 = MFMA(wfh[ks], blB, aB0);
                aB0 = MFMA(wfl[ks], bhB, aB0);
            }
        }
        f32x4 gA = aA0 + aA1 + xva;
        f32x4 gB = aB0 + aB1 + xvb;

        // ---- 2 cells/lane: C regs r = gates {i,f,g,o} of (hid, batA/batB)
        unsigned PA, PB;
        {
            float iv=fsigmoid(gA[0]), fv=fsigmoid(gA[1]);
            float gv=ftanh(gA[2]),    ov=fsigmoid(gA[3]);
            float cn = fv*cA + iv*gv;
            float hn = ov*ftanh(cn); cA = cn;
            unsigned hh = f2bf(hn);
            PA = hh | (f2bf(hn - bf2f(hh)) << 16);
        }
        {
            float iv=fsigmoid(gB[0]), fv=fsigmoid(gB[1]);
            float gv=ftanh(gB[2]),    ov=fsigmoid(gB[3]);
            float cn = fv*cB + iv*gv;
            float hn = ov*ftanh(cn); cB = cn;
            unsigned hh = f2bf(hn);
            PB = hh | (f2bf(hn - bf2f(hh)) << 16);
        }

        // ---- shuffle transpose -> one coalesced 8B publish store per lane
        const int bq = lane & 31, half = lane >> 5;
        const int s0 = bq & 15;
        const bool selA = (bq < 16);
        unsigned q0,q1,q2,q3;
        { unsigned a,b;
          a=__shfl(PA,s0,64);    b=__shfl(PB,s0,64);    q0 = selA?a:b;
          a=__shfl(PA,s0+16,64); b=__shfl(PB,s0+16,64); q1 = selA?a:b;
          a=__shfl(PA,s0+32,64); b=__shfl(PB,s0+32,64); q2 = selA?a:b;
          a=__shfl(PA,s0+48,64); b=__shfl(PB,s0+48,64); q3 = selA?a:b; }
        {
            const int pn = (t+1)&1;
            unsigned w0, w1;
            unsigned short* dst;
            if (half == 0){
                w0 = (q0&0xFFFFu) | (q1<<16);
                w1 = (q2&0xFFFFu) | (q3<<16);
                dst = Hhi + (size_t)pn*16384 + (size_t)bq*512 + W*4;
            } else {
                w0 = (q0>>16) | (q1&0xFFFF0000u);
                w1 = (q2>>16) | (q3&0xFFFF0000u);
                dst = Hlo + (size_t)pn*16384 + (size_t)bq*512 + W*4;
            }
            u32x2 pk; pk[0]=w0; pk[1]=w1;
            asm volatile("global_store_dwordx2 %0, %1, off sc0 sc1"
                         :: "v"(dst), "v"(pk) : "memory");
        }

        __syncthreads();   // drains publish stores + LDS consumption fence
        if (tid == 0){
            unsigned tv = (unsigned)(t+1);
            unsigned* tp = tags + w;
            asm volatile("global_store_dword %0, %1, off sc0 sc1"
                         :: "v"(tp), "v"(tv) : "memory");
            if (w == 0){
                unsigned* pw = cnt + SEQ;
                asm volatile("global_store_dword %0, %1, off sc0 sc1"
                             :: "v"(pw), "v"(tv) : "memory");
            }
        }
        // ---- off-critical-path outputs
        if (half == 0){
            f32x4 hv;
            hv[0] = __uint_as_float(q0<<16) + __uint_as_float(q0&0xFFFF0000u);
            hv[1] = __uint_as_float(q1<<16) + __uint_as_float(q1&0xFFFF0000u);
            hv[2] = __uint_as_float(q2<<16) + __uint_as_float(q2&0xFFFF0000u);
            hv[3] = __uint_as_float(q3<<16) + __uint_as_float(q3&0xFFFF0000u);
            *(f32x4*)(out + (size_t)t*16384 + (size_t)bq*512 + 4*W) = hv;
        } else if (t == SEQ-1){
            f32x4 hv;
            hv[0] = __uint_as_float(q0<<16) + __uint_as_float(q0&0xFFFF0000u);
            hv[1] = __uint_as_float(q1<<16) + __uint_as_float(q1&0xFFFF0000u);
            hv[2] = __uint_as_float(q2<<16) + __uint_as_float(q2&0xFFFF0000u);
            hv[3] = __uint_as_float(q3<<16) + __uint_as_float(q3&0xFFFF0000u);
            *(f32x4*)(out + (size_t)SEQ*16384 + (size_t)bq*512 + 4*W) = hv;
        }
    }

    float* cT = out + (size_t)SEQ*16384 + 16384;
    cT[(size_t)batA*HID + hid] = cA;
    cT[(size_t)batB*HID + hid] = cB;
}

// ---------------------------------------------------------------------------
// xproj role: 224 WGs stream tiles (t, nb) into the ring (row'-permuted,
// bias folded), gated by scan progress P. (R9-proven.)
// ---------------------------------------------------------------------------
__device__ __forceinline__ void xproj_role(
    const float* __restrict__ x, const float* __restrict__ Wih,
    const float* __restrict__ bih, const float* __restrict__ bhh,
    float* __restrict__ xpring, int R, int Rmask,
    unsigned* __restrict__ cnt, const unsigned* __restrict__ Pw,
    char* smem)
{
    const int j   = blockIdx.x - NSCAN;
    const int tid = threadIdx.x;
    float* As = (float*)smem;          // [16][33]
    float* Bs = As + 16*33;            // [16][132]
    const int tx = tid & 15, ty = tid >> 4;

    for (int tau = j; tau < SEQ*16; tau += (NWG - NSCAN)) {
        const int t = tau >> 4, nb = tau & 15, n0 = nb*128;
        const int tneed = t - R + 2;
        if (tneed > 0) {
            while (1) {
                unsigned pv;
                asm volatile("global_load_dword %0, %1, off sc0 sc1\n\t"
                             "s_waitcnt vmcnt(0)"
                             : "=&v"(pv) : "v"(Pw) : "memory");
                if ((int)pv >= tneed) break;
                __builtin_amdgcn_s_sleep(32);
            }
        }
        float bj[8];
#pragma unroll
        for (int q = 0; q < 8; ++q) {
            int rowp = n0 + 8*ty + q;
            int wr = ((rowp & 3) << 9) | (rowp >> 2);
            bj[q] = bih[wr] + bhh[wr];
        }
        float acc[2][8];
#pragma unroll
        for (int i = 0; i < 2; ++i)
#pragma unroll
            for (int q = 0; q < 8; ++q) acc[i][q] = 0.f;

        for (int kc = 0; kc < 512; kc += 16) {
            if (tid < 128) {
                int r = tid >> 2, u = tid & 3;
                f32x4 v = *(const f32x4*)(x + ((size_t)t*32 + r)*512 + kc + 4*u);
                As[(4*u+0)*33 + r] = v[0];
                As[(4*u+1)*33 + r] = v[1];
                As[(4*u+2)*33 + r] = v[2];
                As[(4*u+3)*33 + r] = v[3];
            }
#pragma unroll
            for (int h2 = 0; h2 < 2; ++h2) {
                int idx = tid*2 + h2;
                int r = idx >> 2, u = idx & 3;
                int rowp = n0 + r;
                int wr = ((rowp & 3) << 9) | (rowp >> 2);
                f32x4 v = *(const f32x4*)(Wih + (size_t)wr*512 + kc + 4*u);
                Bs[(4*u+0)*132 + r] = v[0];
                Bs[(4*u+1)*132 + r] = v[1];
                Bs[(4*u+2)*132 + r] = v[2];
                Bs[(4*u+3)*132 + r] = v[3];
            }
            __syncthreads();
#pragma unroll
            for (int kk = 0; kk < 16; ++kk) {
                float a0 = As[kk*33 + 2*tx];
                float a1 = As[kk*33 + 2*tx + 1];
                f32x4 b0 = *(const f32x4*)(Bs + kk*132 + 8*ty);
                f32x4 b1 = *(const f32x4*)(Bs + kk*132 + 8*ty + 4);
#pragma unroll
                for (int q = 0; q < 4; ++q) {
                    acc[0][q]   += a0 * b0[q];
                    acc[0][q+4] += a0 * b1[q];
                    acc[1][q]   += a1 * b0[q];
                    acc[1][q+4] += a1 * b1[q];
                }
            }
            __syncthreads();
        }
        float* dst = xpring + (size_t)(t & Rmask)*65536;
#pragma unroll
        for (int i = 0; i < 2; ++i) {
            int m = 2*tx + i;
            f32x4 v0 = {acc[i][0]+bj[0], acc[i][1]+bj[1],
                        acc[i][2]+bj[2], acc[i][3]+bj[3]};
            f32x4 v1 = {acc[i][4]+bj[4], acc[i][5]+bj[5],
                        acc[i][6]+bj[6], acc[i][7]+bj[7]};
            float* pp = dst + (size_t)m*2048 + n0 + 8*ty;
            asm volatile("global_store_dwordx4 %0, %1, off sc0 sc1"
                         :: "v"(pp), "v"(v0) : "memory");
            asm volatile("global_store_dwordx4 %0, %1, off sc0 sc1"
                         :: "v"(pp+4), "v"(v1) : "memory");
        }
        __syncthreads();                 // drain stores in all waves
        if (tid == 0) atomicAdd(cnt + t, 1u);
    }
}

// ---------------------------------------------------------------------------
__global__ __launch_bounds__(256, 1)
__attribute__((amdgpu_waves_per_eu(1, 1)))
void fused_kernel(const float* __restrict__ x,
                  const float* __restrict__ c0,
                  const float* __restrict__ Wih,
                  const float* __restrict__ Whh,
                  const float* __restrict__ bih,
                  const float* __restrict__ bhh,
                  float* __restrict__ out,
                  unsigned short* __restrict__ Hhi,
                  unsigned short* __restrict__ Hlo,
                  unsigned* __restrict__ tags,
                  unsigned* __restrict__ cnt,
                  float* __restrict__ xpring,
                  int R)
{
    __shared__ char smem[65536];
    unsigned* Pw = cnt + SEQ;
    if (blockIdx.x < NSCAN)
        scan_role(Whh, c0, xpring, R-1, Hhi, Hlo, tags, cnt, out, smem);
    else
        xproj_role(x, Wih, bih, bhh, xpring, R, R-1, cnt, Pw, smem);
}

// ---------------------------------------------------------------------------
extern "C" void kernel_launch(void* const* d_in, const int* in_sizes, int n_in,
                              void* d_out, int out_size, void* d_ws, size_t ws_size,
                              hipStream_t stream)
{
    const float* x   = (const float*)d_in[0];
    const float* h0  = (const float*)d_in[1];
    const float* c0  = (const float*)d_in[2];
    const float* Wih = (const float*)d_in[3];
    const float* Whh = (const float*)d_in[4];
    const float* bih = (const float*)d_in[5];
    const float* bhh = (const float*)d_in[6];
    float* out = (float*)d_out;

    char* base = (char*)d_ws;
    unsigned short* Hhi  = (unsigned short*)base;             // 2 x 32 KB
    unsigned short* Hlo  = (unsigned short*)(base + 65536);   // 2 x 32 KB
    unsigned*       tags = (unsigned*)(base + 131072);        // 128 B (use 32)
    unsigned*       cnt  = (unsigned*)(base + 131584);        // (SEQ+4)*4
    size_t ringoff = (size_t)(131584 + (SEQ+4)*4 + 255) & ~(size_t)255;
    float* xpring = (float*)(base + ringoff);

    size_t avail = (ws_size > ringoff) ? ws_size - ringoff : 0;
    long long Rll = (long long)(avail / (65536ull*4ull));
    int R = (Rll > 256) ? 256 : (int)Rll;
    while (R & (R-1)) R &= R-1;   // pow2 floor
    if (R < 2) R = 2;

    hipLaunchKernelGGL(init_kernel, dim3(64), dim3(256), 0, stream,
                       h0, Hhi, Hlo, tags, cnt);
    hipLaunchKernelGGL(fused_kernel, dim3(NWG), dim3(256), 0, stream,
                       x, c0, Wih, Whh, bih, bhh, out,
                       Hhi, Hlo, tags, cnt, xpring, R);
}